// Round 2
// baseline (1011.488 us; speedup 1.0000x reference)
//
#include <hip/hip_runtime.h>

#define NN 2048   // nodes
#define BB 32     // batch
#define CC 64     // dim_in
#define DD 16     // embed dim
#define OO 64     // dim_out

// ---------------- K1: apt = softmax(relu(E @ E^T), axis=1) ----------------
__global__ __launch_bounds__(256) void apt_kernel(const float* __restrict__ E,
                                                  float* __restrict__ apt) {
  __shared__ __align__(16) float s[NN];
  __shared__ float red[8];
  const int n = blockIdx.x;
  const int t = threadIdx.x;
  const float4* en4 = (const float4*)(E + (size_t)n * DD);
  const float4 e0 = en4[0], e1 = en4[1], e2 = en4[2], e3 = en4[3];
  float lmax = 0.f;
  for (int j = t; j < NN; j += 256) {
    const float4* ej = (const float4*)(E + (size_t)j * DD);
    const float4 a = ej[0], b = ej[1], c = ej[2], d = ej[3];
    float dot = e0.x*a.x + e0.y*a.y + e0.z*a.z + e0.w*a.w;
    dot += e1.x*b.x + e1.y*b.y + e1.z*b.z + e1.w*b.w;
    dot += e2.x*c.x + e2.y*c.y + e2.z*c.z + e2.w*c.w;
    dot += e3.x*d.x + e3.y*d.y + e3.z*d.z + e3.w*d.w;
    dot = fmaxf(dot, 0.f);
    s[j] = dot;
    lmax = fmaxf(lmax, dot);
  }
  #pragma unroll
  for (int off = 32; off > 0; off >>= 1) lmax = fmaxf(lmax, __shfl_down(lmax, off));
  if ((t & 63) == 0) red[t >> 6] = lmax;
  __syncthreads();
  const float gmax = fmaxf(fmaxf(red[0], red[1]), fmaxf(red[2], red[3]));
  float lsum = 0.f;
  for (int j = t; j < NN; j += 256) {
    const float e = __expf(s[j] - gmax);
    s[j] = e;
    lsum += e;
  }
  #pragma unroll
  for (int off = 32; off > 0; off >>= 1) lsum += __shfl_down(lsum, off);
  if ((t & 63) == 0) red[4 + (t >> 6)] = lsum;
  __syncthreads();
  const float inv = 1.f / (red[4] + red[5] + red[6] + red[7]);
  float* aprow = apt + (size_t)n * NN;
  for (int j = t; j < NN; j += 256) aprow[j] = s[j] * inv;
}

// ---------------- batched GEMM: Y[b] = alpha*A@Xin[b] (+ beta*Xadd[b]) ----------------
// A: (NN,NN) shared across batch. Tile: 128 rows x (2 batches * 64 cols), TK=32.
// 256 threads, 8x8 micro-tile, single-stage register prefetch.
#define TM 128
#define TKK 32
__global__ __launch_bounds__(256) void sup_gemm(const float* __restrict__ A,
                                                const float* __restrict__ Xin,
                                                const float* __restrict__ Xadd,
                                                const float alpha, const float beta,
                                                float* __restrict__ Y) {
  __shared__ __align__(16) float As[TKK][TM + 4];      // [k][row] (transposed)
  __shared__ __align__(16) float Bs[TKK][2 * CC + 4];  // [k][2*64 cols]
  const int t = threadIdx.x;
  const int n0 = blockIdx.x * TM;
  const int b0 = blockIdx.y * 2;
  const int tx = t & 15;   // cols tx*4..+3 within each batch half
  const int ty = t >> 4;   // rows ty*8..+7
  float acc[8][8];
  #pragma unroll
  for (int i = 0; i < 8; ++i)
    #pragma unroll
    for (int j = 0; j < 8; ++j) acc[i][j] = 0.f;

  float4 pa[4], pb[4];
  auto load_tile = [&](int kt) {
    #pragma unroll
    for (int i = 0; i < 4; ++i) {
      const int q  = t + 256 * i;
      const int r  = q >> 3;            // 0..127
      const int c4 = (q & 7) * 4;       // 0..28
      pa[i] = *(const float4*)(A + (size_t)(n0 + r) * NN + kt + c4);
      const int rb   = q >> 5;          // 0..31
      const int cb   = (q & 31) * 4;    // 0..124
      const int half = cb >> 6;
      const int col  = cb & 63;
      pb[i] = *(const float4*)(Xin + ((size_t)(b0 + half) * NN + kt + rb) * CC + col);
    }
  };
  auto store_tile = [&]() {
    #pragma unroll
    for (int i = 0; i < 4; ++i) {
      const int q  = t + 256 * i;
      const int r  = q >> 3;
      const int c4 = (q & 7) * 4;
      As[c4 + 0][r] = pa[i].x; As[c4 + 1][r] = pa[i].y;
      As[c4 + 2][r] = pa[i].z; As[c4 + 3][r] = pa[i].w;
      const int rb = q >> 5;
      const int cb = (q & 31) * 4;
      *(float4*)&Bs[rb][cb] = pb[i];
    }
  };

  load_tile(0);
  store_tile();
  __syncthreads();
  for (int kt = 0; kt < NN; kt += TKK) {
    const bool more = (kt + TKK) < NN;
    if (more) load_tile(kt + TKK);   // overlaps with compute below
    #pragma unroll 8
    for (int kk = 0; kk < TKK; ++kk) {
      float av[8], bv[8];
      *(float4*)&av[0] = *(const float4*)&As[kk][ty * 8];
      *(float4*)&av[4] = *(const float4*)&As[kk][ty * 8 + 4];
      *(float4*)&bv[0] = *(const float4*)&Bs[kk][tx * 4];
      *(float4*)&bv[4] = *(const float4*)&Bs[kk][CC + tx * 4];
      #pragma unroll
      for (int i = 0; i < 8; ++i)
        #pragma unroll
        for (int j = 0; j < 8; ++j)
          acc[i][j] = fmaf(av[i], bv[j], acc[i][j]);
    }
    if (more) {
      __syncthreads();
      store_tile();
      __syncthreads();
    }
  }
  // epilogue: j<4 -> batch b0, col tx*4+j ; j>=4 -> batch b0+1, col tx*4+(j-4)
  #pragma unroll
  for (int i = 0; i < 8; ++i) {
    const int r = n0 + ty * 8 + i;
    #pragma unroll
    for (int h = 0; h < 2; ++h) {
      const size_t base = ((size_t)(b0 + h) * NN + r) * CC + tx * 4;
      const float* ap = &acc[i][h * 4];
      float4 v;
      v.x = alpha * ap[0]; v.y = alpha * ap[1];
      v.z = alpha * ap[2]; v.w = alpha * ap[3];
      if (Xadd) {
        const float4 ad = *(const float4*)(Xadd + base);
        v.x = fmaf(beta, ad.x, v.x); v.y = fmaf(beta, ad.y, v.y);
        v.z = fmaf(beta, ad.z, v.z); v.w = fmaf(beta, ad.w, v.w);
      }
      *(float4*)(Y + base) = v;
    }
  }
}

// ---------------- K5: per-node weight gen + mini-GEMM + bias ----------------
// Block per node n: W[n][k][i][o] = sum_d E[n,d]*Wp[d,k,i,o] in LDS (64KB),
// xg rows staged in LDS, out[b,n,o] = sum_{k,i} xg*W + bias.
__global__ __launch_bounds__(256) void out_kernel(const float* __restrict__ x,
                                                  const float* __restrict__ y1,
                                                  const float* __restrict__ y2,
                                                  const float* __restrict__ y3,
                                                  const float* __restrict__ E,
                                                  const float* __restrict__ Wp,
                                                  const float* __restrict__ bp,
                                                  float* __restrict__ out) {
  __shared__ __align__(16) float Wl[4 * 64 * 64];     // [k][i][o], 64 KB
  __shared__ __align__(16) float xgs[4][32][68];      // padded rows
  __shared__ __align__(16) float bias[64];
  __shared__ float en[16];
  const int n = blockIdx.x;
  const int t = threadIdx.x;
  if (t < 16) en[t] = E[(size_t)n * DD + t];
  __syncthreads();
  // W generation (coalesced Wp reads; Wp is 1MB -> L2 resident)
  for (int idx = t; idx < 16384; idx += 256) {
    float a = 0.f;
    #pragma unroll
    for (int d = 0; d < 16; ++d) a = fmaf(en[d], Wp[(size_t)d * 16384 + idx], a);
    Wl[idx] = a;
  }
  if (t < 64) {
    float a = 0.f;
    #pragma unroll
    for (int d = 0; d < 16; ++d) a = fmaf(en[d], bp[d * 64 + t], a);
    bias[t] = a;
  }
  // stage xg[k][b][i] for this n
  float* xgf = (float*)xgs;
  #pragma unroll
  for (int m = 0; m < 32; ++m) {
    const int idx = t + 256 * m;       // k uniform per m
    const int k = idx >> 11;
    const int b = (idx >> 6) & 31;
    const int i = idx & 63;
    const float* src = (k == 0) ? x : (k == 1) ? y1 : (k == 2) ? y2 : y3;
    xgf[(k * 32 + b) * 68 + i] = src[((size_t)b * NN + n) * CC + i];
  }
  __syncthreads();
  // mini-GEMM: thread = (2 batches, 4 outputs)
  const int ob = t & 15;   // o = ob*4..+3
  const int bb = t >> 4;   // b = bb*2, bb*2+1
  float acc0[4] = {0.f, 0.f, 0.f, 0.f}, acc1[4] = {0.f, 0.f, 0.f, 0.f};
  #pragma unroll
  for (int k = 0; k < 4; ++k) {
    const float* xr0 = &xgs[k][bb * 2][0];
    const float* xr1 = &xgs[k][bb * 2 + 1][0];
    const float* wk = &Wl[k * 4096 + ob * 4];
    #pragma unroll 8
    for (int i = 0; i < 64; ++i) {
      const float4 wv = *(const float4*)(wk + i * 64);
      const float xa = xr0[i], xb = xr1[i];
      acc0[0] = fmaf(xa, wv.x, acc0[0]); acc0[1] = fmaf(xa, wv.y, acc0[1]);
      acc0[2] = fmaf(xa, wv.z, acc0[2]); acc0[3] = fmaf(xa, wv.w, acc0[3]);
      acc1[0] = fmaf(xb, wv.x, acc1[0]); acc1[1] = fmaf(xb, wv.y, acc1[1]);
      acc1[2] = fmaf(xb, wv.z, acc1[2]); acc1[3] = fmaf(xb, wv.w, acc1[3]);
    }
  }
  const float4 bi = *(const float4*)&bias[ob * 4];
  float4 v0, v1;
  v0.x = acc0[0] + bi.x; v0.y = acc0[1] + bi.y; v0.z = acc0[2] + bi.z; v0.w = acc0[3] + bi.w;
  v1.x = acc1[0] + bi.x; v1.y = acc1[1] + bi.y; v1.z = acc1[2] + bi.z; v1.w = acc1[3] + bi.w;
  *(float4*)(out + ((size_t)(bb * 2) * NN + n) * CC + ob * 4) = v0;
  *(float4*)(out + ((size_t)(bb * 2 + 1) * NN + n) * CC + ob * 4) = v1;
}

extern "C" void kernel_launch(void* const* d_in, const int* in_sizes, int n_in,
                              void* d_out, int out_size, void* d_ws, size_t ws_size,
                              hipStream_t stream) {
  const float* x   = (const float*)d_in[0];   // (32,2048,64)
  const float* E   = (const float*)d_in[1];   // (2048,16)
  const float* lap = (const float*)d_in[2];   // (2048,2048)
  const float* Wp  = (const float*)d_in[3];   // (16,4,64,64)
  const float* bp  = (const float*)d_in[4];   // (16,64)
  float* out = (float*)d_out;                 // (32,2048,64)

  float* ws  = (float*)d_ws;                  // needs 4*4194304*4B = 64 MiB
  const size_t SEG = (size_t)NN * NN;         // 4194304 (== BB*NN*CC)
  float* apt = ws;
  float* y1  = ws + SEG;
  float* y2  = ws + 2 * SEG;
  float* y3  = ws + 3 * SEG;

  apt_kernel<<<NN, 256, 0, stream>>>(E, apt);
  // y1 = lap @ x
  sup_gemm<<<dim3(NN / TM, BB / 2), 256, 0, stream>>>(lap, x, nullptr, 1.f, 0.f, y1);
  // y3 = apt @ x
  sup_gemm<<<dim3(NN / TM, BB / 2), 256, 0, stream>>>(apt, x, nullptr, 1.f, 0.f, y3);
  // y2 = 2*lap @ y1 - x
  sup_gemm<<<dim3(NN / TM, BB / 2), 256, 0, stream>>>(lap, y1, x, 2.f, -1.f, y2);
  // final: per-node weights + mini-GEMM + bias
  out_kernel<<<NN, 256, 0, stream>>>(x, y1, y2, y3, E, Wp, bp, out);
  (void)in_sizes; (void)n_in; (void)out_size; (void)ws_size;
}

// Round 3
// 405.423 us; speedup vs baseline: 2.4949x; 2.4949x over previous
//
#include <hip/hip_runtime.h>

#define NN 2048   // nodes
#define BB 32     // batch
#define CC 64     // dim_in
#define DD 16     // embed dim

typedef unsigned short u16;
typedef __attribute__((ext_vector_type(8))) short bf8_t;   // 8 bf16 (4 VGPRs)
typedef __attribute__((ext_vector_type(4))) float f4_t;

__device__ __forceinline__ u16 f2bf(float f) {
  unsigned u = __float_as_uint(f);
  return (u16)((u + 0x7fffu + ((u >> 16) & 1u)) >> 16);   // RNE
}
__device__ __forceinline__ float bf2f(u16 u) {
  return __uint_as_float(((unsigned)u) << 16);
}
__device__ __forceinline__ void gload_lds16(const u16* g, u16* l) {
  __builtin_amdgcn_global_load_lds((const __attribute__((address_space(1))) unsigned*)g,
                                   (__attribute__((address_space(3))) unsigned*)l, 16, 0, 0);
}

// ---------------- K1: lap f32 -> bf16 (row-major) ----------------
__global__ __launch_bounds__(256) void cvt_bf16(const float* __restrict__ in,
                                                u16* __restrict__ outp) {
  const size_t i = ((size_t)blockIdx.x * 256 + threadIdx.x) * 8;
  const float4 v0 = *(const float4*)(in + i);
  const float4 v1 = *(const float4*)(in + i + 4);
  ushort4 a, b;
  a.x = f2bf(v0.x); a.y = f2bf(v0.y); a.z = f2bf(v0.z); a.w = f2bf(v0.w);
  b.x = f2bf(v1.x); b.y = f2bf(v1.y); b.z = f2bf(v1.z); b.w = f2bf(v1.w);
  *(ushort4*)(outp + i) = a;
  *(ushort4*)(outp + i + 4) = b;
}

// ---------------- K2: apt = softmax(relu(E @ E^T), axis=1) -> bf16 ----------------
__global__ __launch_bounds__(256) void apt_kernel(const float* __restrict__ E,
                                                  u16* __restrict__ apt) {
  __shared__ __align__(16) float s[NN];
  __shared__ float red[8];
  const int n = blockIdx.x;
  const int t = threadIdx.x;
  const float4* en4 = (const float4*)(E + (size_t)n * DD);
  const float4 e0 = en4[0], e1 = en4[1], e2 = en4[2], e3 = en4[3];
  float lmax = 0.f;
  for (int j = t; j < NN; j += 256) {
    const float4* ej = (const float4*)(E + (size_t)j * DD);
    const float4 a = ej[0], b = ej[1], c = ej[2], d = ej[3];
    float dot = e0.x*a.x + e0.y*a.y + e0.z*a.z + e0.w*a.w;
    dot += e1.x*b.x + e1.y*b.y + e1.z*b.z + e1.w*b.w;
    dot += e2.x*c.x + e2.y*c.y + e2.z*c.z + e2.w*c.w;
    dot += e3.x*d.x + e3.y*d.y + e3.z*d.z + e3.w*d.w;
    dot = fmaxf(dot, 0.f);
    s[j] = dot;
    lmax = fmaxf(lmax, dot);
  }
  #pragma unroll
  for (int off = 32; off > 0; off >>= 1) lmax = fmaxf(lmax, __shfl_down(lmax, off));
  if ((t & 63) == 0) red[t >> 6] = lmax;
  __syncthreads();
  const float gmax = fmaxf(fmaxf(red[0], red[1]), fmaxf(red[2], red[3]));
  float lsum = 0.f;
  for (int j = t; j < NN; j += 256) {
    const float e = __expf(s[j] - gmax);
    s[j] = e;
    lsum += e;
  }
  #pragma unroll
  for (int off = 32; off > 0; off >>= 1) lsum += __shfl_down(lsum, off);
  if ((t & 63) == 0) red[4 + (t >> 6)] = lsum;
  __syncthreads();
  const float inv = 1.f / (red[4] + red[5] + red[6] + red[7]);
  u16* aprow = apt + (size_t)n * NN;
  for (int j = t; j < NN; j += 256) aprow[j] = f2bf(s[j] * inv);
}

// ---------------- K3: transpose f32 (b,2048,64) -> bf16 (b,64,2048) ----------------
__global__ __launch_bounds__(256) void tr_f32_bf16(const float* __restrict__ in,
                                                   u16* __restrict__ outT) {
  __shared__ u16 T[64][65];
  const int b = blockIdx.y, m0 = blockIdx.x * 64, t = threadIdx.x;
  #pragma unroll
  for (int ii = 0; ii < 16; ++ii) {
    const int idx = t + 256 * ii;
    const int r = idx >> 6, c = idx & 63;
    T[c][r] = f2bf(in[((size_t)b * NN + m0 + r) * CC + c]);
  }
  __syncthreads();
  #pragma unroll
  for (int ii = 0; ii < 16; ++ii) {
    const int idx = t + 256 * ii;
    const int c = idx >> 6, r = idx & 63;
    outT[((size_t)b * CC + c) * NN + m0 + r] = T[c][r];
  }
}

// ---------------- K3b: transpose bf16 (b,2048,64) -> bf16 (b,64,2048) ----------------
__global__ __launch_bounds__(256) void tr_bf16(const u16* __restrict__ in,
                                               u16* __restrict__ outT) {
  __shared__ u16 T[64][65];
  const int b = blockIdx.y, m0 = blockIdx.x * 64, t = threadIdx.x;
  #pragma unroll
  for (int ii = 0; ii < 16; ++ii) {
    const int idx = t + 256 * ii;
    const int r = idx >> 6, c = idx & 63;
    T[c][r] = in[((size_t)b * NN + m0 + r) * CC + c];
  }
  __syncthreads();
  #pragma unroll
  for (int ii = 0; ii < 16; ++ii) {
    const int idx = t + 256 * ii;
    const int c = idx >> 6, r = idx & 63;
    outT[((size_t)b * CC + c) * NN + m0 + r] = T[c][r];
  }
}

// ---------------- K4: bf16 MFMA GEMM (B^T input), m97 structure ----------------
// C[n, R] = alpha * sum_m A[n,m] * XT[R,m]  (+ beta*add)  -> bf16 Y (b,m,c) layout
// 128x128 tile, BK=32, 4 waves (2x2 of 64x64), 16x16x32 MFMA.
// LDS [row][32k] bf16, 64B rows; 16B-chunk XOR swizzle: chunk' = chunk ^ ((row>>1)&3)
// applied on BOTH the stage global-source and the ds_read address (involution).
__global__ __launch_bounds__(256) void mfma_gemm(
    const u16* __restrict__ A0, const u16* __restrict__ X0, const float* __restrict__ add0,
    float alpha0, float beta0, u16* __restrict__ Y0,
    const u16* __restrict__ A1, const u16* __restrict__ X1, const float* __restrict__ add1,
    float alpha1, float beta1, u16* __restrict__ Y1) {
  __shared__ __align__(16) u16 Alds[128 * 32];
  __shared__ __align__(16) u16 Blds[128 * 32];
  const int z = blockIdx.z;
  const u16* Ap = z ? A1 : A0;
  const u16* Xp = z ? X1 : X0;
  const float* add = z ? add1 : add0;
  const float alpha = z ? alpha1 : alpha0;
  const float beta = z ? beta1 : beta0;
  u16* Y = z ? Y1 : Y0;

  const int t = threadIdx.x;
  const int n0 = blockIdx.x * 128;      // row tile (nodes)
  const int c0 = blockIdx.y * 128;      // col tile (flat b*64+c)

  const int l = t & 63;
  const int w = t >> 6;
  const int lr = l & 15;                // frag row/col lane index
  const int lg = l >> 4;                // k-chunk group 0..3
  const int wr = (w >> 1) * 64, wc = (w & 1) * 64;

  // per-frag swizzled LDS byte offsets
  int aoff[4], boff[4];
  #pragma unroll
  for (int f = 0; f < 4; ++f) {
    const int r = wr + f * 16 + lr;
    aoff[f] = r * 64 + ((lg ^ ((r >> 1) & 3)) * 16);
    const int c = wc + f * 16 + lr;
    boff[f] = c * 64 + ((lg ^ ((c >> 1) & 3)) * 16);
  }

  f4_t acc[4][4];
  const f4_t zf = {0.f, 0.f, 0.f, 0.f};
  #pragma unroll
  for (int i = 0; i < 4; ++i)
    #pragma unroll
    for (int j = 0; j < 4; ++j) acc[i][j] = zf;

  auto stage = [&](int kt) {
    #pragma unroll
    for (int i = 0; i < 2; ++i) {
      const int q = i * 256 + t;          // 16B-chunk index 0..511
      const int r = q >> 2, ch = q & 3;
      const int cg = ch ^ ((r >> 1) & 3); // swizzled source chunk
      gload_lds16(Ap + (size_t)(n0 + r) * NN + kt + cg * 8, &Alds[q * 8]);
      gload_lds16(Xp + (size_t)(c0 + r) * NN + kt + cg * 8, &Blds[q * 8]);
    }
  };

  stage(0);
  for (int kt = 0; kt < NN; kt += 32) {
    __syncthreads();                       // compiler drains vmcnt before barrier
    bf8_t a[4], b[4];
    #pragma unroll
    for (int f = 0; f < 4; ++f) a[f] = *(const bf8_t*)((const char*)Alds + aoff[f]);
    #pragma unroll
    for (int f = 0; f < 4; ++f) b[f] = *(const bf8_t*)((const char*)Blds + boff[f]);
    __syncthreads();                       // lgkm drained: reads done, safe to restage
    if (kt + 32 < NN) stage(kt + 32);      // overlaps with MFMAs below
    #pragma unroll
    for (int i = 0; i < 4; ++i)
      #pragma unroll
      for (int j = 0; j < 4; ++j)
        acc[i][j] = __builtin_amdgcn_mfma_f32_16x16x32_bf16(a[i], b[j], acc[i][j], 0, 0, 0);
  }

  // epilogue: C/D layout col=lane&15, row=(lane>>4)*4+reg  [m89-verified]
  #pragma unroll
  for (int i = 0; i < 4; ++i) {
    #pragma unroll
    for (int j = 0; j < 4; ++j) {
      const int col = c0 + wc + j * 16 + lr;
      const int bb = col >> 6, cc = col & 63;
      #pragma unroll
      for (int v = 0; v < 4; ++v) {
        const int row = n0 + wr + i * 16 + lg * 4 + v;
        const size_t o = ((size_t)bb * NN + row) * CC + cc;
        float val = alpha * acc[i][j][v];
        if (add) val = fmaf(beta, add[o], val);
        Y[o] = f2bf(val);
      }
    }
  }
}

// ---------------- K5: per-node weight gen + mini-GEMM + bias (2 nodes/block) ----------------
__global__ __launch_bounds__(256) void out_kernel(const float* __restrict__ x,
                                                  const u16* __restrict__ y1,
                                                  const u16* __restrict__ y2,
                                                  const u16* __restrict__ y3,
                                                  const float* __restrict__ E,
                                                  const float* __restrict__ Wp,
                                                  const float* __restrict__ bp,
                                                  float* __restrict__ out) {
  __shared__ __align__(16) u16 Wl[2][16384];       // 64 KB bf16 weights
  __shared__ __align__(16) float xgs[2][4][32][66];
  __shared__ float bias[2][64];
  __shared__ float en[2][16];
  const int n0 = blockIdx.x * 2;
  const int t = threadIdx.x;
  if (t < 32) en[t >> 4][t & 15] = E[(size_t)(n0 + (t >> 4)) * DD + (t & 15)];
  __syncthreads();
  // W-gen: read each Wp element once, serve both nodes
  for (int idx = t; idx < 16384; idx += 256) {
    float a0 = 0.f, a1 = 0.f;
    #pragma unroll
    for (int d = 0; d < 16; ++d) {
      const float wv = Wp[(size_t)d * 16384 + idx];
      a0 = fmaf(en[0][d], wv, a0);
      a1 = fmaf(en[1][d], wv, a1);
    }
    Wl[0][idx] = f2bf(a0);
    Wl[1][idx] = f2bf(a1);
  }
  if (t < 128) {
    const int nl = t >> 6, o = t & 63;
    float a = 0.f;
    #pragma unroll
    for (int d = 0; d < 16; ++d) a = fmaf(en[nl][d], bp[d * 64 + o], a);
    bias[nl][o] = a;
  }
  // xg staging: [2 nodes][4 k][32 b][64 i]
  #pragma unroll 4
  for (int m = 0; m < 64; ++m) {
    const int idx = t + 256 * m;
    const int nl = idx >> 13, k = (idx >> 11) & 3, b = (idx >> 6) & 31, i = idx & 63;
    const size_t src = ((size_t)b * NN + n0 + nl) * CC + i;
    float v;
    if (k == 0) v = x[src];
    else if (k == 1) v = bf2f(y1[src]);
    else if (k == 2) v = bf2f(y2[src]);
    else v = bf2f(y3[src]);
    xgs[nl][k][b][i] = v;
  }
  __syncthreads();
  // mini-GEMM: thread = (node, 4 batches, 4 outputs)
  const int nl = t >> 7, tt = t & 127;
  const int ob = tt & 15;   // o = ob*4..+3
  const int bq = tt >> 4;   // b = bq*4..+3
  float acc[4][4];
  #pragma unroll
  for (int i = 0; i < 4; ++i)
    #pragma unroll
    for (int j = 0; j < 4; ++j) acc[i][j] = 0.f;
  #pragma unroll
  for (int k = 0; k < 4; ++k) {
    #pragma unroll 8
    for (int i = 0; i < 64; ++i) {
      const ushort4 wu = *(const ushort4*)&Wl[nl][k * 4096 + i * 64 + ob * 4];
      const float w0 = bf2f(wu.x), w1 = bf2f(wu.y), w2 = bf2f(wu.z), w3 = bf2f(wu.w);
      #pragma unroll
      for (int bb = 0; bb < 4; ++bb) {
        const float xa = xgs[nl][k][bq * 4 + bb][i];
        acc[bb][0] = fmaf(xa, w0, acc[bb][0]);
        acc[bb][1] = fmaf(xa, w1, acc[bb][1]);
        acc[bb][2] = fmaf(xa, w2, acc[bb][2]);
        acc[bb][3] = fmaf(xa, w3, acc[bb][3]);
      }
    }
  }
  #pragma unroll
  for (int bb = 0; bb < 4; ++bb) {
    float4 v;
    v.x = acc[bb][0] + bias[nl][ob * 4 + 0];
    v.y = acc[bb][1] + bias[nl][ob * 4 + 1];
    v.z = acc[bb][2] + bias[nl][ob * 4 + 2];
    v.w = acc[bb][3] + bias[nl][ob * 4 + 3];
    *(float4*)(out + ((size_t)(bq * 4 + bb) * NN + n0 + nl) * CC + ob * 4) = v;
  }
}

extern "C" void kernel_launch(void* const* d_in, const int* in_sizes, int n_in,
                              void* d_out, int out_size, void* d_ws, size_t ws_size,
                              hipStream_t stream) {
  const float* x   = (const float*)d_in[0];   // (32,2048,64)
  const float* E   = (const float*)d_in[1];   // (2048,16)
  const float* lap = (const float*)d_in[2];   // (2048,2048)
  const float* Wp  = (const float*)d_in[3];   // (16,4,64,64)
  const float* bp  = (const float*)d_in[4];   // (16,64)
  float* out = (float*)d_out;                 // (32,2048,64)

  // ws layout (56 MiB total; ws gave us >=64 MiB in round 2)
  char* ws = (char*)d_ws;
  const size_t SEG = (size_t)NN * NN * sizeof(u16);  // 8 MiB
  u16* lapB = (u16*)(ws);
  u16* aptB = (u16*)(ws + SEG);
  u16* xT   = (u16*)(ws + 2 * SEG);
  u16* y1n  = (u16*)(ws + 3 * SEG);
  u16* y1T  = (u16*)(ws + 4 * SEG);
  u16* y2n  = (u16*)(ws + 5 * SEG);
  u16* y3n  = (u16*)(ws + 6 * SEG);

  cvt_bf16<<<2048, 256, 0, stream>>>(lap, lapB);
  apt_kernel<<<NN, 256, 0, stream>>>(E, aptB);
  tr_f32_bf16<<<dim3(32, 32), 256, 0, stream>>>(x, xT);
  // G1: y1 = lap @ x
  mfma_gemm<<<dim3(16, 16, 1), 256, 0, stream>>>(
      lapB, xT, nullptr, 1.f, 0.f, y1n,
      nullptr, nullptr, nullptr, 0.f, 0.f, nullptr);
  tr_bf16<<<dim3(32, 32), 256, 0, stream>>>(y1n, y1T);
  // G2: y2 = 2*lap@y1 - x ; G3: y3 = apt @ x  (fused, grid.z=2 -> 512 blocks)
  mfma_gemm<<<dim3(16, 16, 2), 256, 0, stream>>>(
      lapB, y1T, x, 2.f, -1.f, y2n,
      aptB, xT, nullptr, 1.f, 0.f, y3n);
  out_kernel<<<NN / 2, 256, 0, stream>>>(x, y1n, y2n, y3n, E, Wp, bp, out);
  (void)in_sizes; (void)n_in; (void)out_size; (void)ws_size;
}

// Round 14
// 351.245 us; speedup vs baseline: 2.8797x; 1.1542x over previous
//
#include <hip/hip_runtime.h>

#define NN 2048   // nodes
#define BB 32     // batch
#define CC 64     // dim_in
#define DD 16     // embed dim

typedef unsigned short u16;
typedef __attribute__((ext_vector_type(8))) short bf8_t;   // 8 bf16 (4 VGPRs)
typedef __attribute__((ext_vector_type(4))) float f4_t;

__device__ __forceinline__ u16 f2bf(float f) {
  unsigned u = __float_as_uint(f);
  return (u16)((u + 0x7fffu + ((u >> 16) & 1u)) >> 16);   // RNE
}
__device__ __forceinline__ float bf2f(u16 u) {
  return __uint_as_float(((unsigned)u) << 16);
}
__device__ __forceinline__ void gload_lds16(const u16* g, u16* l) {
  __builtin_amdgcn_global_load_lds((const __attribute__((address_space(1))) unsigned*)g,
                                   (__attribute__((address_space(3))) unsigned*)l, 16, 0, 0);
}

// ---------------- K1: lap f32 -> bf16 (row-major) ----------------
__global__ __launch_bounds__(256) void cvt_bf16(const float* __restrict__ in,
                                                u16* __restrict__ outp) {
  const size_t i = ((size_t)blockIdx.x * 256 + threadIdx.x) * 8;
  const float4 v0 = *(const float4*)(in + i);
  const float4 v1 = *(const float4*)(in + i + 4);
  ushort4 a, b;
  a.x = f2bf(v0.x); a.y = f2bf(v0.y); a.z = f2bf(v0.z); a.w = f2bf(v0.w);
  b.x = f2bf(v1.x); b.y = f2bf(v1.y); b.z = f2bf(v1.z); b.w = f2bf(v1.w);
  *(ushort4*)(outp + i) = a;
  *(ushort4*)(outp + i + 4) = b;
}

// ---------------- K2: apt = softmax(relu(E @ E^T), axis=1) -> bf16 ----------------
__global__ __launch_bounds__(256) void apt_kernel(const float* __restrict__ E,
                                                  u16* __restrict__ apt) {
  __shared__ __align__(16) float s[NN];
  __shared__ float red[8];
  const int n = blockIdx.x;
  const int t = threadIdx.x;
  const float4* en4 = (const float4*)(E + (size_t)n * DD);
  const float4 e0 = en4[0], e1 = en4[1], e2 = en4[2], e3 = en4[3];
  float lmax = 0.f;
  for (int j = t; j < NN; j += 256) {
    const float4* ej = (const float4*)(E + (size_t)j * DD);
    const float4 a = ej[0], b = ej[1], c = ej[2], d = ej[3];
    float dot = e0.x*a.x + e0.y*a.y + e0.z*a.z + e0.w*a.w;
    dot += e1.x*b.x + e1.y*b.y + e1.z*b.z + e1.w*b.w;
    dot += e2.x*c.x + e2.y*c.y + e2.z*c.z + e2.w*c.w;
    dot += e3.x*d.x + e3.y*d.y + e3.z*d.z + e3.w*d.w;
    dot = fmaxf(dot, 0.f);
    s[j] = dot;
    lmax = fmaxf(lmax, dot);
  }
  #pragma unroll
  for (int off = 32; off > 0; off >>= 1) lmax = fmaxf(lmax, __shfl_down(lmax, off));
  if ((t & 63) == 0) red[t >> 6] = lmax;
  __syncthreads();
  const float gmax = fmaxf(fmaxf(red[0], red[1]), fmaxf(red[2], red[3]));
  float lsum = 0.f;
  for (int j = t; j < NN; j += 256) {
    const float e = __expf(s[j] - gmax);
    s[j] = e;
    lsum += e;
  }
  #pragma unroll
  for (int off = 32; off > 0; off >>= 1) lsum += __shfl_down(lsum, off);
  if ((t & 63) == 0) red[4 + (t >> 6)] = lsum;
  __syncthreads();
  const float inv = 1.f / (red[4] + red[5] + red[6] + red[7]);
  u16* aprow = apt + (size_t)n * NN;
  for (int j = t; j < NN; j += 256) aprow[j] = f2bf(s[j] * inv);
}

// ---------------- K3: x f32 (b,2048,64) -> xT bf16 (b,64,2048) + xB bf16 (b,2048,64) ----------------
__global__ __launch_bounds__(256) void trx_kernel(const float* __restrict__ in,
                                                  u16* __restrict__ outT,
                                                  u16* __restrict__ outB) {
  __shared__ u16 T[64][65];
  const int b = blockIdx.y, m0 = blockIdx.x * 64, t = threadIdx.x;
  #pragma unroll
  for (int ii = 0; ii < 16; ++ii) {
    const int idx = t + 256 * ii;
    const int r = idx >> 6, c = idx & 63;
    const u16 v = f2bf(in[((size_t)b * NN + m0 + r) * CC + c]);
    T[c][r] = v;
    outB[((size_t)b * NN + m0 + r) * CC + c] = v;
  }
  __syncthreads();
  #pragma unroll
  for (int ii = 0; ii < 16; ++ii) {
    const int idx = t + 256 * ii;
    const int c = idx >> 6, r = idx & 63;
    outT[((size_t)b * CC + c) * NN + m0 + r] = T[c][r];
  }
}

// ---------------- K3b: transpose bf16 (b,2048,64) -> bf16 (b,64,2048) ----------------
__global__ __launch_bounds__(256) void tr_bf16(const u16* __restrict__ in,
                                               u16* __restrict__ outT) {
  __shared__ u16 T[64][65];
  const int b = blockIdx.y, m0 = blockIdx.x * 64, t = threadIdx.x;
  #pragma unroll
  for (int ii = 0; ii < 16; ++ii) {
    const int idx = t + 256 * ii;
    const int r = idx >> 6, c = idx & 63;
    T[c][r] = in[((size_t)b * NN + m0 + r) * CC + c];
  }
  __syncthreads();
  #pragma unroll
  for (int ii = 0; ii < 16; ++ii) {
    const int idx = t + 256 * ii;
    const int c = idx >> 6, r = idx & 63;
    outT[((size_t)b * CC + c) * NN + m0 + r] = T[c][r];
  }
}

// ---------------- K4: bf16 MFMA GEMM (B^T input), m97 structure ----------------
__global__ __launch_bounds__(256) void mfma_gemm(
    const u16* __restrict__ A0, const u16* __restrict__ X0, const float* __restrict__ add0,
    float alpha0, float beta0, u16* __restrict__ Y0,
    const u16* __restrict__ A1, const u16* __restrict__ X1, const float* __restrict__ add1,
    float alpha1, float beta1, u16* __restrict__ Y1) {
  __shared__ __align__(16) u16 Alds[128 * 32];
  __shared__ __align__(16) u16 Blds[128 * 32];
  const int z = blockIdx.z;
  const u16* Ap = z ? A1 : A0;
  const u16* Xp = z ? X1 : X0;
  const float* add = z ? add1 : add0;
  const float alpha = z ? alpha1 : alpha0;
  const float beta = z ? beta1 : beta0;
  u16* Y = z ? Y1 : Y0;

  const int t = threadIdx.x;
  const int n0 = blockIdx.x * 128;      // row tile (nodes)
  const int c0 = blockIdx.y * 128;      // col tile (flat b*64+c)

  const int l = t & 63;
  const int w = t >> 6;
  const int lr = l & 15;
  const int lg = l >> 4;
  const int wr = (w >> 1) * 64, wc = (w & 1) * 64;

  int aoff[4], boff[4];
  #pragma unroll
  for (int f = 0; f < 4; ++f) {
    const int r = wr + f * 16 + lr;
    aoff[f] = r * 64 + ((lg ^ ((r >> 1) & 3)) * 16);
    const int c = wc + f * 16 + lr;
    boff[f] = c * 64 + ((lg ^ ((c >> 1) & 3)) * 16);
  }

  f4_t acc[4][4];
  const f4_t zf = {0.f, 0.f, 0.f, 0.f};
  #pragma unroll
  for (int i = 0; i < 4; ++i)
    #pragma unroll
    for (int j = 0; j < 4; ++j) acc[i][j] = zf;

  auto stage = [&](int kt) {
    #pragma unroll
    for (int i = 0; i < 2; ++i) {
      const int q = i * 256 + t;
      const int r = q >> 2, ch = q & 3;
      const int cg = ch ^ ((r >> 1) & 3);
      gload_lds16(Ap + (size_t)(n0 + r) * NN + kt + cg * 8, &Alds[q * 8]);
      gload_lds16(Xp + (size_t)(c0 + r) * NN + kt + cg * 8, &Blds[q * 8]);
    }
  };

  stage(0);
  for (int kt = 0; kt < NN; kt += 32) {
    __syncthreads();
    bf8_t a[4], b[4];
    #pragma unroll
    for (int f = 0; f < 4; ++f) a[f] = *(const bf8_t*)((const char*)Alds + aoff[f]);
    #pragma unroll
    for (int f = 0; f < 4; ++f) b[f] = *(const bf8_t*)((const char*)Blds + boff[f]);
    __syncthreads();
    if (kt + 32 < NN) stage(kt + 32);
    #pragma unroll
    for (int i = 0; i < 4; ++i)
      #pragma unroll
      for (int j = 0; j < 4; ++j)
        acc[i][j] = __builtin_amdgcn_mfma_f32_16x16x32_bf16(a[i], b[j], acc[i][j], 0, 0, 0);
  }

  #pragma unroll
  for (int i = 0; i < 4; ++i) {
    #pragma unroll
    for (int j = 0; j < 4; ++j) {
      const int col = c0 + wc + j * 16 + lr;
      const int bb = col >> 6, cc = col & 63;
      #pragma unroll
      for (int v = 0; v < 4; ++v) {
        const int row = n0 + wr + i * 16 + lg * 4 + v;
        const size_t o = ((size_t)bb * NN + row) * CC + cc;
        float val = alpha * acc[i][j][v];
        if (add) val = fmaf(beta, add[o], val);
        Y[o] = f2bf(val);
      }
    }
  }
}

// ---------------- K5: Wt[local n][o][ki] = sum_d E[n,d]*Wp[d][ki][o]  (bf16, o-major) ----------------
// 8 nodes/block; Wp staged per 32-ki chunk in LDS (bf16, o XOR-swizzled vs ki).
// BUGFIX (round 12 post-mortem): Wt is a 1024-node LOCAL buffer -> write at
// (blockIdx.x*8 + nn), NOT the global node id (n0base+...). The global-id write
// was overrunning Wth by 32 MiB on the second half, clobbering y1n/y2n/y3n/xB.
__global__ __launch_bounds__(256) void wgen_kernel(const float* __restrict__ E,
                                                   const float* __restrict__ Wp,
                                                   u16* __restrict__ Wt, int n0base) {
  __shared__ u16 wp[16][32][64];   // 64 KB, o index swizzled: o ^ ((ki&7)<<3)
  __shared__ float es[8][16];
  const int t = threadIdx.x;
  const int ng = n0base + blockIdx.x * 8;   // global node base (E reads)
  const int nl = blockIdx.x * 8;            // local node base (Wt writes)
  if (t < 128) es[t >> 4][t & 15] = E[(size_t)(ng + (t >> 4)) * DD + (t & 15)];
  const int ki = t & 31, og = t >> 5;
  for (int kc = 0; kc < 8; ++kc) {
    __syncthreads();
    // stage chunk: Wp[16 d][32 ki][64 o] -> bf16 LDS
    #pragma unroll 8
    for (int jj = 0; jj < 32; ++jj) {
      const int idx4 = jj * 256 + t;
      const int e = idx4 * 4;
      const int d = e >> 11, rem = e & 2047, kk = rem >> 6, o = rem & 63;
      const float4 v = *(const float4*)(Wp + (size_t)d * 16384 + (size_t)(kc * 32 + kk) * 64 + o);
      ushort4 u;
      u.x = f2bf(v.x); u.y = f2bf(v.y); u.z = f2bf(v.z); u.w = f2bf(v.w);
      *(ushort4*)&wp[d][kk][o ^ ((kk & 7) << 3)] = u;
    }
    __syncthreads();
    // compute + write (lanes consecutive in ki -> 64B write segments)
    for (int oo = 0; oo < 8; ++oo) {
      const int o = og * 8 + oo;
      float wv[16];
      #pragma unroll
      for (int d = 0; d < 16; ++d) wv[d] = bf2f(wp[d][ki][o ^ ((ki & 7) << 3)]);
      #pragma unroll
      for (int nn = 0; nn < 8; ++nn) {
        float a = 0.f;
        #pragma unroll
        for (int d = 0; d < 16; ++d) a = fmaf(es[nn][d], wv[d], a);
        Wt[(size_t)(nl + nn) * 16384 + o * 256 + kc * 32 + ki] = f2bf(a);
      }
    }
  }
}

// ---------------- K6: final per-node MFMA: out[b,n,o] = xg[b,ki] @ Wt[n][o,ki]^T + bias ----------------
// 1 node/block. LDS 48KB -> 3 blocks/CU. Chunk-XOR swizzle ch^(row&7) on stage-src + read.
__global__ __launch_bounds__(256) void final_kernel(const u16* __restrict__ xB,
                                                    const u16* __restrict__ y1,
                                                    const u16* __restrict__ y2,
                                                    const u16* __restrict__ y3,
                                                    const u16* __restrict__ Wt,
                                                    const float* __restrict__ E,
                                                    const float* __restrict__ bp,
                                                    float* __restrict__ out, int nbase) {
  __shared__ __align__(16) u16 Wl[64 * 256];    // [o][ki] 32 KB
  __shared__ __align__(16) u16 xga[32 * 256];   // [b][ki] 16 KB
  __shared__ float bias[64];
  const int n = nbase + blockIdx.x;
  const int t = threadIdx.x;
  const u16* wsrc = Wt + (size_t)(n - nbase) * 16384;
  #pragma unroll
  for (int j = 0; j < 8; ++j) {
    const int q = j * 256 + t;
    const int r = q >> 5, ch = q & 31;
    const int cg = ch ^ (r & 7);
    gload_lds16(wsrc + r * 256 + cg * 8, &Wl[q * 8]);
  }
  #pragma unroll
  for (int j = 0; j < 4; ++j) {
    const int q = j * 256 + t;
    const int r = q >> 5, ch = q & 31;
    const int cg = ch ^ (r & 7);
    const int kbuf = cg >> 3, i = (cg & 7) * 8;
    const u16* src = (kbuf == 0) ? xB : (kbuf == 1) ? y1 : (kbuf == 2) ? y2 : y3;
    gload_lds16(src + ((size_t)r * NN + n) * CC + i, &xga[q * 8]);
  }
  if (t < 64) {
    float a = 0.f;
    #pragma unroll
    for (int d = 0; d < 16; ++d) a = fmaf(E[(size_t)n * DD + d], bp[d * 64 + t], a);
    bias[t] = a;
  }
  __syncthreads();

  const int l = t & 63, w = t >> 6;
  const int lr = l & 15, lg = l >> 4;
  const int mt = w >> 1;                 // m-tile (b = mt*16 + lr)
  const int nb = (w & 1) * 2;            // n-tiles nb, nb+1
  const int arow = mt * 16 + lr;
  const int brow0 = nb * 16 + lr, brow1 = (nb + 1) * 16 + lr;
  f4_t acc0 = {0.f, 0.f, 0.f, 0.f}, acc1 = {0.f, 0.f, 0.f, 0.f};
  #pragma unroll
  for (int kt = 0; kt < 8; ++kt) {
    const int c = kt * 4 + lg;
    const bf8_t a  = *(const bf8_t*)&xga[arow * 256 + (c ^ (arow & 7)) * 8];
    const bf8_t b0 = *(const bf8_t*)&Wl[brow0 * 256 + (c ^ (brow0 & 7)) * 8];
    const bf8_t b1 = *(const bf8_t*)&Wl[brow1 * 256 + (c ^ (brow1 & 7)) * 8];
    acc0 = __builtin_amdgcn_mfma_f32_16x16x32_bf16(a, b0, acc0, 0, 0, 0);
    acc1 = __builtin_amdgcn_mfma_f32_16x16x32_bf16(a, b1, acc1, 0, 0, 0);
  }
  const int o0 = nb * 16 + lr, o1 = (nb + 1) * 16 + lr;
  #pragma unroll
  for (int v = 0; v < 4; ++v) {
    const int b = mt * 16 + lg * 4 + v;
    out[((size_t)b * NN + n) * CC + o0] = acc0[v] + bias[o0];
    out[((size_t)b * NN + n) * CC + o1] = acc1[v] + bias[o1];
  }
}

extern "C" void kernel_launch(void* const* d_in, const int* in_sizes, int n_in,
                              void* d_out, int out_size, void* d_ws, size_t ws_size,
                              hipStream_t stream) {
  const float* x   = (const float*)d_in[0];   // (32,2048,64)
  const float* E   = (const float*)d_in[1];   // (2048,16)
  const float* lap = (const float*)d_in[2];   // (2048,2048)
  const float* Wp  = (const float*)d_in[3];   // (16,4,64,64)
  const float* bp  = (const float*)d_in[4];   // (16,64)
  float* out = (float*)d_out;                 // (32,2048,64)

  // ws: 8 segs x 8 MiB = 64 MiB (proven available in round 2)
  char* ws = (char*)d_ws;
  const size_t SEG = (size_t)NN * NN * sizeof(u16);  // 8 MiB
  u16* lapB = (u16*)(ws);             // seg0  (dead after G2G3)
  u16* aptB = (u16*)(ws + SEG);       // seg1  (dead after G2G3)
  u16* xT   = (u16*)(ws + 2 * SEG);   // seg2  (dead after G2G3)
  u16* y1T  = (u16*)(ws + 3 * SEG);   // seg3  (dead after G2G3)
  u16* y1n  = (u16*)(ws + 4 * SEG);   // seg4
  u16* y2n  = (u16*)(ws + 5 * SEG);   // seg5
  u16* y3n  = (u16*)(ws + 6 * SEG);   // seg6
  u16* xB   = (u16*)(ws + 7 * SEG);   // seg7
  u16* Wth  = (u16*)(ws);             // segs 0-3 reused: 32 MiB = 1024 LOCAL nodes x 32 KB

  cvt_bf16<<<2048, 256, 0, stream>>>(lap, lapB);
  apt_kernel<<<NN, 256, 0, stream>>>(E, aptB);
  trx_kernel<<<dim3(32, 32), 256, 0, stream>>>(x, xT, xB);
  // G1: y1 = lap @ x
  mfma_gemm<<<dim3(16, 16, 1), 256, 0, stream>>>(
      lapB, xT, nullptr, 1.f, 0.f, y1n,
      nullptr, nullptr, nullptr, 0.f, 0.f, nullptr);
  tr_bf16<<<dim3(32, 32), 256, 0, stream>>>(y1n, y1T);
  // G2: y2 = 2*lap@y1 - x ; G3: y3 = apt @ x  (fused via grid.z)
  mfma_gemm<<<dim3(16, 16, 2), 256, 0, stream>>>(
      lapB, y1T, x, 2.f, -1.f, y2n,
      aptB, xT, nullptr, 1.f, 0.f, y3n);
  // out-path in two node-halves (Wt reuses segs 0-3; local indexing inside wgen)
  wgen_kernel<<<128, 256, 0, stream>>>(E, Wp, Wth, 0);
  final_kernel<<<1024, 256, 0, stream>>>(xB, y1n, y2n, y3n, Wth, E, bp, out, 0);
  wgen_kernel<<<128, 256, 0, stream>>>(E, Wp, Wth, 1024);
  final_kernel<<<1024, 256, 0, stream>>>(xB, y1n, y2n, y3n, Wth, E, bp, out, 1024);
  (void)in_sizes; (void)n_in; (void)out_size; (void)ws_size;
}